// Round 10
// baseline (2503.666 us; speedup 1.0000x reference)
//
#include <hip/hip_runtime.h>
#include <hip/hip_bf16.h>

#define NN 100000
#define EE 1600000
#define DOUT 40
#define LN_EPS 1e-5f
#define NB 391     // (NN+255)/256 scan blocks
#define NBUCK 391  // buckets of 256 dst nodes
#define TILE 16384

typedef __attribute__((ext_vector_type(8))) short short8;   // 8 bf16 = 4 VGPRs
typedef __attribute__((ext_vector_type(4))) float f32x4;    // MFMA acc

// ---------------------------------------------------------------- bf16 helpers (RNE pack)
__device__ __forceinline__ float blo(unsigned u) { return __uint_as_float(u << 16); }
__device__ __forceinline__ float bhi(unsigned u) { return __uint_as_float(u & 0xffff0000u); }
__device__ __forceinline__ unsigned bpack(float lo, float hi) {
    unsigned a = __float_as_uint(lo);
    unsigned b = __float_as_uint(hi);
    a = (a + 0x7fffu + ((a >> 16) & 1u)) >> 16;
    b = (b + 0x7fffu + ((b >> 16) & 1u)) & 0xffff0000u;
    return (a & 0xffffu) | b;
}

// ---------------------------------------------------------------- degree + scan (cursor = start offsets)
__global__ void hist_k(const int* __restrict__ dst, int* __restrict__ degI) {
    int e = blockIdx.x * 256 + threadIdx.x;
    if (e < EE) atomicAdd(&degI[dst[e]], 1);
}

__global__ void dinv_k(const int* __restrict__ degI, float* __restrict__ dinv) {
    int n = blockIdx.x * 256 + threadIdx.x;
    if (n < NN) dinv[n] = rsqrtf((float)degI[n] + 1.0f);
}

__global__ void scan1_k(const int* __restrict__ degI, int* __restrict__ cursor,
                        int* __restrict__ bsum) {
    __shared__ int s[256];
    int tid = threadIdx.x;
    int i = blockIdx.x * 256 + tid;
    int v = (i < NN) ? degI[i] : 0;
    s[tid] = v;
    __syncthreads();
    for (int off = 1; off < 256; off <<= 1) {
        int t = (tid >= off) ? s[tid - off] : 0;
        __syncthreads();
        s[tid] += t;
        __syncthreads();
    }
    if (i < NN) cursor[i] = s[tid] - v;
    if (tid == 255) bsum[blockIdx.x] = s[255];
}

__global__ void scan2_k(int* __restrict__ bsum) {
    __shared__ int s[512];
    int tid = threadIdx.x;
    int v = (tid < NB) ? bsum[tid] : 0;
    s[tid] = v;
    __syncthreads();
    for (int off = 1; off < 512; off <<= 1) {
        int t = (tid >= off) ? s[tid - off] : 0;
        __syncthreads();
        s[tid] += t;
        __syncthreads();
    }
    if (tid < NB) bsum[tid] = s[tid] - v;
}

__global__ void scan3_k(int* __restrict__ cursor, const int* __restrict__ bsum) {
    int i = blockIdx.x * 256 + threadIdx.x;
    if (i < NN) cursor[i] += bsum[blockIdx.x];
}

// ---------------------------------------------------------------- bucket build
__global__ void binit_k(const int* __restrict__ cursor, int* __restrict__ bucketCur) {
    int b = blockIdx.x * 256 + threadIdx.x;
    if (b < NBUCK) bucketCur[b] = cursor[b << 8];
}

// two-pass tile bucketing; per-tile per-bucket chunks claimed with ONE global
// atomic -> chunk-exclusive writes (no cross-XCD line bouncing).
__global__ void bucket_k(const int* __restrict__ src, const int* __restrict__ dst,
                         int* __restrict__ bucketCur, unsigned* __restrict__ bE) {
    __shared__ int cnt[NBUCK];
    __shared__ int cnt2[NBUCK];
    __shared__ int base[NBUCK];
    int tid = threadIdx.x;
    for (int i = tid; i < NBUCK; i += 256) { cnt[i] = 0; cnt2[i] = 0; }
    __syncthreads();
    long e0 = (long)blockIdx.x * TILE;
    for (int i = tid; i < TILE; i += 256) {
        long e = e0 + i;
        if (e < EE) atomicAdd(&cnt[dst[e] >> 8], 1);
    }
    __syncthreads();
    for (int i = tid; i < NBUCK; i += 256)
        base[i] = atomicAdd(&bucketCur[i], cnt[i]);
    __syncthreads();
    for (int i = tid; i < TILE; i += 256) {
        long e = e0 + i;
        if (e < EE) {
            int d = dst[e];
            int b = d >> 8;
            int pos = base[b] + atomicAdd(&cnt2[b], 1);
            bE[pos] = (unsigned)src[e] | ((unsigned)(d & 255) << 24);
        }
    }
}

// ---------------------------------------------------------------- MFMA GEMM: H' = bf16((X@W)*dinv)
template <int K>
__global__ __launch_bounds__(256, 2) void gemm_mfma(const float* __restrict__ X,
                                                    const float* __restrict__ W,
                                                    const float* __restrict__ dinv,
                                                    unsigned* __restrict__ H) {
    constexpr int C = K / 32;
    __shared__ unsigned short sW16[K * 66];
    __shared__ float sD[64 * 65];
    int tid = threadIdx.x;
    for (int i = tid; i < K * 64; i += 256) {
        int k = i >> 6, n = i & 63;
        sW16[k * 66 + n] = (unsigned short)(bpack(W[i], 0.f) & 0xffffu);
    }
    __syncthreads();
    int wv = tid >> 6, lane = tid & 63;
    int q = lane >> 4, ln = lane & 15;
    short8 bfrag[C][4];
#pragma unroll
    for (int c = 0; c < C; ++c) {
#pragma unroll
        for (int t = 0; t < 4; ++t) {
            int kb = (c * 32 + q * 8) * 66 + t * 16 + ln;
            unsigned u0 = (unsigned)sW16[kb]       | ((unsigned)sW16[kb + 66]  << 16);
            unsigned u1 = (unsigned)sW16[kb + 132] | ((unsigned)sW16[kb + 198] << 16);
            unsigned u2 = (unsigned)sW16[kb + 264] | ((unsigned)sW16[kb + 330] << 16);
            unsigned u3 = (unsigned)sW16[kb + 396] | ((unsigned)sW16[kb + 462] << 16);
            uint4 u = make_uint4(u0, u1, u2, u3);
            bfrag[c][t] = __builtin_bit_cast(short8, u);
        }
    }
    int base = blockIdx.x * 64;
    int node = base + wv * 16 + ln;
    bool ok = node < NN;
    short8 afrag[C];
#pragma unroll
    for (int c = 0; c < C; ++c) {
        float4 f0 = make_float4(0.f, 0.f, 0.f, 0.f);
        float4 f1 = make_float4(0.f, 0.f, 0.f, 0.f);
        if (ok) {
            const float4* xp = (const float4*)(X + (long)node * K + c * 32 + q * 8);
            f0 = xp[0];
            f1 = xp[1];
        }
        uint4 u;
        u.x = bpack(f0.x, f0.y);
        u.y = bpack(f0.z, f0.w);
        u.z = bpack(f1.x, f1.y);
        u.w = bpack(f1.z, f1.w);
        afrag[c] = __builtin_bit_cast(short8, u);
    }
#pragma unroll
    for (int t = 0; t < 4; ++t) {
        f32x4 acc = {0.f, 0.f, 0.f, 0.f};
#pragma unroll
        for (int c = 0; c < C; ++c)
            acc = __builtin_amdgcn_mfma_f32_16x16x32_bf16(afrag[c], bfrag[c][t], acc, 0, 0, 0);
#pragma unroll
        for (int r = 0; r < 4; ++r)
            sD[(wv * 16 + q * 4 + r) * 65 + t * 16 + ln] = acc[r];
    }
    __syncthreads();
    for (int i = tid; i < 64 * 32; i += 256) {
        int row = i >> 5, c2 = i & 31;
        int nd = base + row;
        if (nd < NN) {
            float di = dinv[nd];
            float lo = sD[row * 65 + c2 * 2] * di;
            float hi = sD[row * 65 + c2 * 2 + 1] * di;
            H[nd * 32 + c2] = bpack(lo, hi);
        }
    }
}

// ---------------------------------------------------------------- bucketed aggregate (LDS accumulator)
// One block per bucket (256 dst nodes). lane = g*8+f8: g = edge slot (0..7),
// f8 = feature-octet; lane gathers uint4 (8 bf16). 2-deep unroll -> 16
// gathers in flight per wave. acc stride 66 floats randomizes atomic banks.
__global__ __launch_bounds__(256, 2) void aggB_k(
        const int* __restrict__ cursor, const unsigned* __restrict__ bE,
        const float* __restrict__ dinv, const uint4* __restrict__ H4,
        const float* __restrict__ bias, const float* __restrict__ gam,
        const float* __restrict__ bet, float* __restrict__ OUT, int doLN) {
    __shared__ float acc[256 * 66];
    int tid = threadIdx.x;
    int nodeBase = blockIdx.x << 8;
    for (int i = tid; i < 256 * 66; i += 256) acc[i] = 0.f;
    __syncthreads();
    int start = cursor[nodeBase];
    int end = (blockIdx.x == NBUCK - 1) ? EE : cursor[nodeBase + 256];
    int wv = tid >> 6, lane = tid & 63;
    int g = lane >> 3, f8 = lane & 7;
    for (int e = start + wv * 8 + g; e < end; e += 64) {
        unsigned v0 = bE[e];
        uint4 q0 = H4[(long)(v0 & 0xFFFFFFu) * 8 + f8];
        int e1 = e + 32;
        bool p1 = e1 < end;
        unsigned v1 = bE[p1 ? e1 : e];
        uint4 q1 = H4[(long)(v1 & 0xFFFFFFu) * 8 + f8];
        float* a0 = &acc[(v0 >> 24) * 66 + f8 * 8];
        atomicAdd(a0 + 0, blo(q0.x)); atomicAdd(a0 + 1, bhi(q0.x));
        atomicAdd(a0 + 2, blo(q0.y)); atomicAdd(a0 + 3, bhi(q0.y));
        atomicAdd(a0 + 4, blo(q0.z)); atomicAdd(a0 + 5, bhi(q0.z));
        atomicAdd(a0 + 6, blo(q0.w)); atomicAdd(a0 + 7, bhi(q0.w));
        if (p1) {
            float* a1 = &acc[(v1 >> 24) * 66 + f8 * 8];
            atomicAdd(a1 + 0, blo(q1.x)); atomicAdd(a1 + 1, bhi(q1.x));
            atomicAdd(a1 + 2, blo(q1.y)); atomicAdd(a1 + 3, bhi(q1.y));
            atomicAdd(a1 + 4, blo(q1.z)); atomicAdd(a1 + 5, bhi(q1.z));
            atomicAdd(a1 + 6, blo(q1.w)); atomicAdd(a1 + 7, bhi(q1.w));
        }
    }
    __syncthreads();
    // epilogue: lane = feature
    float bb = bias[lane];
    float gg = doLN ? gam[lane] : 0.f;
    float tt = doLN ? bet[lane] : 0.f;
    const unsigned short* H16 = (const unsigned short*)H4;
    for (int n = wv; n < 256; n += 4) {
        int node = nodeBase + n;
        if (node >= NN) break;
        float a = acc[n * 66 + lane];
        float self = __uint_as_float((unsigned)H16[(long)node * 64 + lane] << 16);
        float di = dinv[node];
        float v = fmaxf((a + self) * di + bb, 0.f);
        if (doLN) {
            float s = v;
            s += __shfl_xor(s, 1); s += __shfl_xor(s, 2); s += __shfl_xor(s, 4);
            s += __shfl_xor(s, 8); s += __shfl_xor(s, 16); s += __shfl_xor(s, 32);
            float mu = s * (1.f / 64.f);
            float dv = v - mu;
            float vs = dv * dv;
            vs += __shfl_xor(vs, 1); vs += __shfl_xor(vs, 2); vs += __shfl_xor(vs, 4);
            vs += __shfl_xor(vs, 8); vs += __shfl_xor(vs, 16); vs += __shfl_xor(vs, 32);
            float inv = rsqrtf(vs * (1.f / 64.f) + LN_EPS);
            v = dv * inv * gg + tt;
        }
        OUT[(long)node * 64 + lane] = v;
    }
}

// ---------------------------------------------------------------- fuse the two head linears
__global__ void fuse_k(const float* __restrict__ W0, const float* __restrict__ b0,
                       const float* __restrict__ W1, const float* __restrict__ b1,
                       float* __restrict__ Wf, float* __restrict__ bf) {
    int tid = threadIdx.x;
    for (int i = tid; i < 64 * 48; i += 256) {
        int k = i / 48, n = i % 48;
        float acc = 0.f;
        if (n < DOUT) {
            for (int j = 0; j < 64; ++j) acc = fmaf(W0[k * 64 + j], W1[j * DOUT + n], acc);
        }
        Wf[i] = acc;
    }
    for (int n = tid; n < 48; n += 256) {
        float acc = 0.f;
        if (n < DOUT) {
            acc = b1[n];
            for (int j = 0; j < 64; ++j) acc = fmaf(b0[j], W1[j * DOUT + n], acc);
        }
        bf[n] = acc;
    }
}

// ---------------------------------------------------------------- MLP head via MFMA: OUT = Hin @ Wf + bf
__global__ __launch_bounds__(256, 2) void mlp_mfma(const float* __restrict__ Hin,
                                                   const float* __restrict__ Wf,
                                                   const float* __restrict__ bf,
                                                   float* __restrict__ OUT) {
    __shared__ unsigned short sW16[64 * 50];
    int tid = threadIdx.x;
    for (int i = tid; i < 64 * 48; i += 256) {
        int k = i / 48, n = i % 48;
        sW16[k * 50 + n] = (unsigned short)(bpack(Wf[i], 0.f) & 0xffffu);
    }
    __syncthreads();
    int wv = tid >> 6, lane = tid & 63;
    int q = lane >> 4, ln = lane & 15;
    short8 bfrag[2][3];
#pragma unroll
    for (int c = 0; c < 2; ++c) {
#pragma unroll
        for (int t = 0; t < 3; ++t) {
            int kb = (c * 32 + q * 8) * 50 + t * 16 + ln;
            unsigned u0 = (unsigned)sW16[kb]       | ((unsigned)sW16[kb + 50]  << 16);
            unsigned u1 = (unsigned)sW16[kb + 100] | ((unsigned)sW16[kb + 150] << 16);
            unsigned u2 = (unsigned)sW16[kb + 200] | ((unsigned)sW16[kb + 250] << 16);
            unsigned u3 = (unsigned)sW16[kb + 300] | ((unsigned)sW16[kb + 350] << 16);
            uint4 u = make_uint4(u0, u1, u2, u3);
            bfrag[c][t] = __builtin_bit_cast(short8, u);
        }
    }
    int base = blockIdx.x * 64;
    int node = base + wv * 16 + ln;
    bool ok = node < NN;
    short8 afrag[2];
#pragma unroll
    for (int c = 0; c < 2; ++c) {
        float4 f0 = make_float4(0.f, 0.f, 0.f, 0.f);
        float4 f1 = make_float4(0.f, 0.f, 0.f, 0.f);
        if (ok) {
            const float4* xp = (const float4*)(Hin + (long)node * 64 + c * 32 + q * 8);
            f0 = xp[0];
            f1 = xp[1];
        }
        uint4 u;
        u.x = bpack(f0.x, f0.y);
        u.y = bpack(f0.z, f0.w);
        u.z = bpack(f1.x, f1.y);
        u.w = bpack(f1.z, f1.w);
        afrag[c] = __builtin_bit_cast(short8, u);
    }
#pragma unroll
    for (int t = 0; t < 3; ++t) {
        f32x4 acc = {0.f, 0.f, 0.f, 0.f};
        acc = __builtin_amdgcn_mfma_f32_16x16x32_bf16(afrag[0], bfrag[0][t], acc, 0, 0, 0);
        acc = __builtin_amdgcn_mfma_f32_16x16x32_bf16(afrag[1], bfrag[1][t], acc, 0, 0, 0);
        int col = t * 16 + ln;
        if (col < DOUT) {
            float bv = bf[col];
#pragma unroll
            for (int r = 0; r < 4; ++r) {
                int nd = base + wv * 16 + q * 4 + r;
                if (nd < NN) OUT[(long)nd * DOUT + col] = acc[r] + bv;
            }
        }
    }
}

// ----------------------------------------------------------------
extern "C" void kernel_launch(void* const* d_in, const int* in_sizes, int n_in,
                              void* d_out, int out_size, void* d_ws, size_t ws_size,
                              hipStream_t stream) {
    const float* x    = (const float*)d_in[0];
    const int*   ei   = (const int*)d_in[1];
    const int*   srcI = ei;
    const int*   dstI = ei + EE;
    const float* W0   = (const float*)d_in[2];
    const float* b0   = (const float*)d_in[3];
    const float* W1   = (const float*)d_in[4];
    const float* b1   = (const float*)d_in[5];
    const float* W2   = (const float*)d_in[6];
    const float* b2   = (const float*)d_in[7];
    const float* ln0g = (const float*)d_in[8];
    const float* ln0b = (const float*)d_in[9];
    const float* ln1g = (const float*)d_in[10];
    const float* ln1b = (const float*)d_in[11];
    const float* mpW0 = (const float*)d_in[12];
    const float* mpb0 = (const float*)d_in[13];
    const float* mpW1 = (const float*)d_in[14];
    const float* mpb1 = (const float*)d_in[15];
    float* out = (float*)d_out;

    char* ws = (char*)d_ws;
    float*    dinv      = (float*)   (ws + 0);
    int*      degI      = (int*)     (ws + 512l * 1024);
    int*      cursor    = (int*)     (ws + 1024l * 1024);
    int*      bsum      = (int*)     (ws + 1536l * 1024);
    int*      bucketCur = (int*)     (ws + 1600l * 1024);
    float*    Wf        = (float*)   (ws + 1792l * 1024);
    float*    bfv       = (float*)   (ws + 1984l * 1024);
    unsigned* bE        = (unsigned*)(ws + 2048l * 1024);       // 6.4 MB packed edges
    unsigned* bufA      = (unsigned*)(ws + 9l * 1024 * 1024);   // bf16 H'  12.8 MB
    float*    bufB      = (float*)   (ws + 23l * 1024 * 1024);  // f32 hidden 25.6 MB

    const int edgeBlocks = (EE + 255) / 256;
    const int gemmBlocks = (NN + 63) / 64;    // 1563
    const int tileBlocks = (EE + TILE - 1) / TILE;  // 98

    hipMemsetAsync(degI, 0, NN * sizeof(int), stream);
    hist_k<<<edgeBlocks, 256, 0, stream>>>(dstI, degI);
    dinv_k<<<NB, 256, 0, stream>>>(degI, dinv);
    scan1_k<<<NB, 256, 0, stream>>>(degI, cursor, bsum);
    scan2_k<<<1, 512, 0, stream>>>(bsum);
    scan3_k<<<NB, 256, 0, stream>>>(cursor, bsum);
    binit_k<<<2, 256, 0, stream>>>(cursor, bucketCur);
    bucket_k<<<tileBlocks, 256, 0, stream>>>(srcI, dstI, bucketCur, bE);
    fuse_k<<<1, 256, 0, stream>>>(mpW0, mpb0, mpW1, mpb1, Wf, bfv);

    // layer 0
    gemm_mfma<128><<<gemmBlocks, 256, 0, stream>>>(x, W0, dinv, bufA);
    aggB_k<<<NBUCK, 256, 0, stream>>>(cursor, bE, dinv, (const uint4*)bufA,
                                      b0, ln0g, ln0b, bufB, 1);
    // layer 1
    gemm_mfma<64><<<gemmBlocks, 256, 0, stream>>>(bufB, W1, dinv, bufA);
    aggB_k<<<NBUCK, 256, 0, stream>>>(cursor, bE, dinv, (const uint4*)bufA,
                                      b1, ln1g, ln1b, bufB, 1);
    // layer 2 (no LN) then fused MLP head via MFMA
    gemm_mfma<64><<<gemmBlocks, 256, 0, stream>>>(bufB, W2, dinv, bufA);
    aggB_k<<<NBUCK, 256, 0, stream>>>(cursor, bE, dinv, (const uint4*)bufA,
                                      b2, ln0g, ln0b, bufB, 0);
    mlp_mfma<<<gemmBlocks, 256, 0, stream>>>(bufB, Wf, bfv, out);
}

// Round 11
// 493.768 us; speedup vs baseline: 5.0705x; 5.0705x over previous
//
#include <hip/hip_runtime.h>
#include <hip/hip_bf16.h>

#define NN 100000
#define EE 1600000
#define DOUT 40
#define LN_EPS 1e-5f
#define NB 391     // (NN+255)/256 scan blocks
#define NBUCK 391  // buckets of 256 dst nodes
#define TILE 16384

typedef __attribute__((ext_vector_type(8))) short short8;   // 8 bf16 = 4 VGPRs
typedef __attribute__((ext_vector_type(4))) float f32x4;    // MFMA acc

// ---------------------------------------------------------------- bf16 helpers (RNE pack)
__device__ __forceinline__ float blo(unsigned u) { return __uint_as_float(u << 16); }
__device__ __forceinline__ float bhi(unsigned u) { return __uint_as_float(u & 0xffff0000u); }
__device__ __forceinline__ unsigned bpack(float lo, float hi) {
    unsigned a = __float_as_uint(lo);
    unsigned b = __float_as_uint(hi);
    a = (a + 0x7fffu + ((a >> 16) & 1u)) >> 16;
    b = (b + 0x7fffu + ((b >> 16) & 1u)) & 0xffff0000u;
    return (a & 0xffffu) | b;
}

// ---------------------------------------------------------------- degree + scan (cursor = START offsets)
__global__ void hist_k(const int* __restrict__ dst, int* __restrict__ degI) {
    int e = blockIdx.x * 256 + threadIdx.x;
    if (e < EE) atomicAdd(&degI[dst[e]], 1);
}

__global__ void dinv_k(const int* __restrict__ degI, float* __restrict__ dinv) {
    int n = blockIdx.x * 256 + threadIdx.x;
    if (n < NN) dinv[n] = rsqrtf((float)degI[n] + 1.0f);
}

__global__ void scan1_k(const int* __restrict__ degI, int* __restrict__ cursor,
                        int* __restrict__ bsum) {
    __shared__ int s[256];
    int tid = threadIdx.x;
    int i = blockIdx.x * 256 + tid;
    int v = (i < NN) ? degI[i] : 0;
    s[tid] = v;
    __syncthreads();
    for (int off = 1; off < 256; off <<= 1) {
        int t = (tid >= off) ? s[tid - off] : 0;
        __syncthreads();
        s[tid] += t;
        __syncthreads();
    }
    if (i < NN) cursor[i] = s[tid] - v;
    if (tid == 255) bsum[blockIdx.x] = s[255];
}

__global__ void scan2_k(int* __restrict__ bsum) {
    __shared__ int s[512];
    int tid = threadIdx.x;
    int v = (tid < NB) ? bsum[tid] : 0;
    s[tid] = v;
    __syncthreads();
    for (int off = 1; off < 512; off <<= 1) {
        int t = (tid >= off) ? s[tid - off] : 0;
        __syncthreads();
        s[tid] += t;
        __syncthreads();
    }
    if (tid < NB) bsum[tid] = s[tid] - v;
}

__global__ void scan3_k(int* __restrict__ cursor, const int* __restrict__ bsum) {
    int i = blockIdx.x * 256 + threadIdx.x;
    if (i < NN) cursor[i] += bsum[blockIdx.x];
}

// ---------------------------------------------------------------- bucket build (chunk-exclusive writes, proven clean)
__global__ void binit_k(const int* __restrict__ cursor, int* __restrict__ bucketCur) {
    int b = blockIdx.x * 256 + threadIdx.x;
    if (b < NBUCK) bucketCur[b] = cursor[b << 8];
}

__global__ void bucket_k(const int* __restrict__ src, const int* __restrict__ dst,
                         int* __restrict__ bucketCur, unsigned* __restrict__ bE) {
    __shared__ int cnt[NBUCK];
    __shared__ int cnt2[NBUCK];
    __shared__ int base[NBUCK];
    int tid = threadIdx.x;
    for (int i = tid; i < NBUCK; i += 256) { cnt[i] = 0; cnt2[i] = 0; }
    __syncthreads();
    long e0 = (long)blockIdx.x * TILE;
    for (int i = tid; i < TILE; i += 256) {
        long e = e0 + i;
        if (e < EE) atomicAdd(&cnt[dst[e] >> 8], 1);
    }
    __syncthreads();
    for (int i = tid; i < NBUCK; i += 256)
        base[i] = atomicAdd(&bucketCur[i], cnt[i]);
    __syncthreads();
    for (int i = tid; i < TILE; i += 256) {
        long e = e0 + i;
        if (e < EE) {
            int d = dst[e];
            int b = d >> 8;
            int pos = base[b] + atomicAdd(&cnt2[b], 1);
            bE[pos] = (unsigned)src[e] | ((unsigned)(d & 255) << 24);
        }
    }
}

// ---------------------------------------------------------------- bucket -> exact CSR (writes stay in one 16KB window)
__global__ void reorder2_k(const int* __restrict__ cursor, const unsigned* __restrict__ bE,
                           int* __restrict__ csrSrc) {
    __shared__ int sStart[256];
    __shared__ int sCnt[256];
    int tid = threadIdx.x;
    int nodeBase = blockIdx.x << 8;
    int nd = nodeBase + tid;
    sStart[tid] = (tid < 256) ? ((nd < NN) ? cursor[nd] : EE) : 0;
    sCnt[tid] = 0;
    __syncthreads();
    int start = cursor[nodeBase];
    int end = (blockIdx.x == NBUCK - 1) ? EE : cursor[nodeBase + 256];
    for (int e = start + tid; e < end; e += 256) {
        unsigned v = bE[e];
        int dl = v >> 24;
        int pos = sStart[dl] + atomicAdd(&sCnt[dl], 1);
        csrSrc[pos] = (int)(v & 0xFFFFFFu);
    }
}

// ---------------------------------------------------------------- MFMA GEMM: H' = bf16((X@W)*dinv)
template <int K>
__global__ __launch_bounds__(256, 2) void gemm_mfma(const float* __restrict__ X,
                                                    const float* __restrict__ W,
                                                    const float* __restrict__ dinv,
                                                    unsigned* __restrict__ H) {
    constexpr int C = K / 32;
    __shared__ unsigned short sW16[K * 66];
    __shared__ float sD[64 * 65];
    int tid = threadIdx.x;
    for (int i = tid; i < K * 64; i += 256) {
        int k = i >> 6, n = i & 63;
        sW16[k * 66 + n] = (unsigned short)(bpack(W[i], 0.f) & 0xffffu);
    }
    __syncthreads();
    int wv = tid >> 6, lane = tid & 63;
    int q = lane >> 4, ln = lane & 15;
    short8 bfrag[C][4];
#pragma unroll
    for (int c = 0; c < C; ++c) {
#pragma unroll
        for (int t = 0; t < 4; ++t) {
            int kb = (c * 32 + q * 8) * 66 + t * 16 + ln;
            unsigned u0 = (unsigned)sW16[kb]       | ((unsigned)sW16[kb + 66]  << 16);
            unsigned u1 = (unsigned)sW16[kb + 132] | ((unsigned)sW16[kb + 198] << 16);
            unsigned u2 = (unsigned)sW16[kb + 264] | ((unsigned)sW16[kb + 330] << 16);
            unsigned u3 = (unsigned)sW16[kb + 396] | ((unsigned)sW16[kb + 462] << 16);
            uint4 u = make_uint4(u0, u1, u2, u3);
            bfrag[c][t] = __builtin_bit_cast(short8, u);
        }
    }
    int base = blockIdx.x * 64;
    int node = base + wv * 16 + ln;
    bool ok = node < NN;
    short8 afrag[C];
#pragma unroll
    for (int c = 0; c < C; ++c) {
        float4 f0 = make_float4(0.f, 0.f, 0.f, 0.f);
        float4 f1 = make_float4(0.f, 0.f, 0.f, 0.f);
        if (ok) {
            const float4* xp = (const float4*)(X + (long)node * K + c * 32 + q * 8);
            f0 = xp[0];
            f1 = xp[1];
        }
        uint4 u;
        u.x = bpack(f0.x, f0.y);
        u.y = bpack(f0.z, f0.w);
        u.z = bpack(f1.x, f1.y);
        u.w = bpack(f1.z, f1.w);
        afrag[c] = __builtin_bit_cast(short8, u);
    }
#pragma unroll
    for (int t = 0; t < 4; ++t) {
        f32x4 acc = {0.f, 0.f, 0.f, 0.f};
#pragma unroll
        for (int c = 0; c < C; ++c)
            acc = __builtin_amdgcn_mfma_f32_16x16x32_bf16(afrag[c], bfrag[c][t], acc, 0, 0, 0);
#pragma unroll
        for (int r = 0; r < 4; ++r)
            sD[(wv * 16 + q * 4 + r) * 65 + t * 16 + ln] = acc[r];
    }
    __syncthreads();
    for (int i = tid; i < 64 * 32; i += 256) {
        int row = i >> 5, c2 = i & 31;
        int nd = base + row;
        if (nd < NN) {
            float di = dinv[nd];
            float lo = sD[row * 65 + c2 * 2] * di;
            float hi = sD[row * 65 + c2 * 2 + 1] * di;
            H[nd * 32 + c2] = bpack(lo, hi);
        }
    }
}

// ---------------------------------------------------------------- aggregate + bias + relu + optional LN (R8-proven)
__global__ __launch_bounds__(256, 4) void agg_k(
        const int* __restrict__ cursor, const int* __restrict__ degI,
        const int* __restrict__ csrSrc, const float* __restrict__ dinv,
        const uint2* __restrict__ H2, const float4* __restrict__ bias4,
        const float4* __restrict__ g4, const float4* __restrict__ beta4,
        float4* __restrict__ OUT4, int doLN) {
    int tid = threadIdx.x;
    int w = tid >> 6, lane = tid & 63;
    int g = lane >> 4;
    int f = lane & 15;
    int node = blockIdx.x * 4 + w;
    int start = cursor[node];
    int end = start + degI[node];
    float ax = 0.f, ay = 0.f, az = 0.f, aw = 0.f;
    float bx = 0.f, by = 0.f, bz = 0.f, bw = 0.f;
    int e = start + g;
    for (; e + 4 < end; e += 8) {
        int s0 = csrSrc[e];
        int s1 = csrSrc[e + 4];
        uint2 q0 = H2[(long)s0 * 16 + f];
        uint2 q1 = H2[(long)s1 * 16 + f];
        ax += blo(q0.x); ay += bhi(q0.x); az += blo(q0.y); aw += bhi(q0.y);
        bx += blo(q1.x); by += bhi(q1.x); bz += blo(q1.y); bw += bhi(q1.y);
    }
    if (e < end) {
        uint2 q0 = H2[(long)csrSrc[e] * 16 + f];
        ax += blo(q0.x); ay += bhi(q0.x); az += blo(q0.y); aw += bhi(q0.y);
    }
    ax += bx; ay += by; az += bz; aw += bw;
    ax += __shfl_xor(ax, 16); ay += __shfl_xor(ay, 16);
    az += __shfl_xor(az, 16); aw += __shfl_xor(aw, 16);
    ax += __shfl_xor(ax, 32); ay += __shfl_xor(ay, 32);
    az += __shfl_xor(az, 32); aw += __shfl_xor(aw, 32);
    float di = dinv[node];
    uint2 qs = H2[(long)node * 16 + f];
    float4 bb = bias4[f];
    float vx = fmaxf((ax + blo(qs.x)) * di + bb.x, 0.f);
    float vy = fmaxf((ay + bhi(qs.x)) * di + bb.y, 0.f);
    float vz = fmaxf((az + blo(qs.y)) * di + bb.z, 0.f);
    float vw = fmaxf((aw + bhi(qs.y)) * di + bb.w, 0.f);
    if (doLN) {
        float s = vx + vy + vz + vw;
        s += __shfl_xor(s, 1); s += __shfl_xor(s, 2);
        s += __shfl_xor(s, 4); s += __shfl_xor(s, 8);
        float mu = s * (1.f / 64.f);
        vx -= mu; vy -= mu; vz -= mu; vw -= mu;
        float vs = vx * vx + vy * vy + vz * vz + vw * vw;
        vs += __shfl_xor(vs, 1); vs += __shfl_xor(vs, 2);
        vs += __shfl_xor(vs, 4); vs += __shfl_xor(vs, 8);
        float inv = rsqrtf(vs * (1.f / 64.f) + LN_EPS);
        float4 gg = g4[f];
        float4 tt = beta4[f];
        vx = vx * inv * gg.x + tt.x;
        vy = vy * inv * gg.y + tt.y;
        vz = vz * inv * gg.z + tt.z;
        vw = vw * inv * gg.w + tt.w;
    }
    if (g == 0) OUT4[(long)node * 16 + f] = make_float4(vx, vy, vz, vw);
}

// ---------------------------------------------------------------- fuse the two head linears
__global__ void fuse_k(const float* __restrict__ W0, const float* __restrict__ b0,
                       const float* __restrict__ W1, const float* __restrict__ b1,
                       float* __restrict__ Wf, float* __restrict__ bf) {
    int tid = threadIdx.x;
    for (int i = tid; i < 64 * 48; i += 256) {
        int k = i / 48, n = i % 48;
        float acc = 0.f;
        if (n < DOUT) {
            for (int j = 0; j < 64; ++j) acc = fmaf(W0[k * 64 + j], W1[j * DOUT + n], acc);
        }
        Wf[i] = acc;
    }
    for (int n = tid; n < 48; n += 256) {
        float acc = 0.f;
        if (n < DOUT) {
            acc = b1[n];
            for (int j = 0; j < 64; ++j) acc = fmaf(b0[j], W1[j * DOUT + n], acc);
        }
        bf[n] = acc;
    }
}

// ---------------------------------------------------------------- MLP head via MFMA: OUT = Hin @ Wf + bf
__global__ __launch_bounds__(256, 2) void mlp_mfma(const float* __restrict__ Hin,
                                                   const float* __restrict__ Wf,
                                                   const float* __restrict__ bf,
                                                   float* __restrict__ OUT) {
    __shared__ unsigned short sW16[64 * 50];
    int tid = threadIdx.x;
    for (int i = tid; i < 64 * 48; i += 256) {
        int k = i / 48, n = i % 48;
        sW16[k * 50 + n] = (unsigned short)(bpack(Wf[i], 0.f) & 0xffffu);
    }
    __syncthreads();
    int wv = tid >> 6, lane = tid & 63;
    int q = lane >> 4, ln = lane & 15;
    short8 bfrag[2][3];
#pragma unroll
    for (int c = 0; c < 2; ++c) {
#pragma unroll
        for (int t = 0; t < 3; ++t) {
            int kb = (c * 32 + q * 8) * 50 + t * 16 + ln;
            unsigned u0 = (unsigned)sW16[kb]       | ((unsigned)sW16[kb + 50]  << 16);
            unsigned u1 = (unsigned)sW16[kb + 100] | ((unsigned)sW16[kb + 150] << 16);
            unsigned u2 = (unsigned)sW16[kb + 200] | ((unsigned)sW16[kb + 250] << 16);
            unsigned u3 = (unsigned)sW16[kb + 300] | ((unsigned)sW16[kb + 350] << 16);
            uint4 u = make_uint4(u0, u1, u2, u3);
            bfrag[c][t] = __builtin_bit_cast(short8, u);
        }
    }
    int base = blockIdx.x * 64;
    int node = base + wv * 16 + ln;
    bool ok = node < NN;
    short8 afrag[2];
#pragma unroll
    for (int c = 0; c < 2; ++c) {
        float4 f0 = make_float4(0.f, 0.f, 0.f, 0.f);
        float4 f1 = make_float4(0.f, 0.f, 0.f, 0.f);
        if (ok) {
            const float4* xp = (const float4*)(Hin + (long)node * 64 + c * 32 + q * 8);
            f0 = xp[0];
            f1 = xp[1];
        }
        uint4 u;
        u.x = bpack(f0.x, f0.y);
        u.y = bpack(f0.z, f0.w);
        u.z = bpack(f1.x, f1.y);
        u.w = bpack(f1.z, f1.w);
        afrag[c] = __builtin_bit_cast(short8, u);
    }
#pragma unroll
    for (int t = 0; t < 3; ++t) {
        f32x4 acc = {0.f, 0.f, 0.f, 0.f};
        acc = __builtin_amdgcn_mfma_f32_16x16x32_bf16(afrag[0], bfrag[0][t], acc, 0, 0, 0);
        acc = __builtin_amdgcn_mfma_f32_16x16x32_bf16(afrag[1], bfrag[1][t], acc, 0, 0, 0);
        int col = t * 16 + ln;
        if (col < DOUT) {
            float bv = bf[col];
#pragma unroll
            for (int r = 0; r < 4; ++r) {
                int nd = base + wv * 16 + q * 4 + r;
                if (nd < NN) OUT[(long)nd * DOUT + col] = acc[r] + bv;
            }
        }
    }
}

// ----------------------------------------------------------------
extern "C" void kernel_launch(void* const* d_in, const int* in_sizes, int n_in,
                              void* d_out, int out_size, void* d_ws, size_t ws_size,
                              hipStream_t stream) {
    const float* x    = (const float*)d_in[0];
    const int*   ei   = (const int*)d_in[1];
    const int*   srcI = ei;
    const int*   dstI = ei + EE;
    const float* W0   = (const float*)d_in[2];
    const float* b0   = (const float*)d_in[3];
    const float* W1   = (const float*)d_in[4];
    const float* b1   = (const float*)d_in[5];
    const float* W2   = (const float*)d_in[6];
    const float* b2   = (const float*)d_in[7];
    const float* ln0g = (const float*)d_in[8];
    const float* ln0b = (const float*)d_in[9];
    const float* ln1g = (const float*)d_in[10];
    const float* ln1b = (const float*)d_in[11];
    const float* mpW0 = (const float*)d_in[12];
    const float* mpb0 = (const float*)d_in[13];
    const float* mpW1 = (const float*)d_in[14];
    const float* mpb1 = (const float*)d_in[15];
    float* out = (float*)d_out;

    char* ws = (char*)d_ws;
    float*    dinv      = (float*)   (ws + 0);
    int*      degI      = (int*)     (ws + 512l * 1024);
    int*      cursor    = (int*)     (ws + 1024l * 1024);
    int*      bsum      = (int*)     (ws + 1536l * 1024);
    int*      bucketCur = (int*)     (ws + 1600l * 1024);
    float*    Wf        = (float*)   (ws + 1792l * 1024);
    float*    bfv       = (float*)   (ws + 1984l * 1024);
    unsigned* bE        = (unsigned*)(ws + 2048l * 1024);           // 6.4 MB packed edges
    int*      csrSrc    = (int*)     (ws + 8704l * 1024);           // 6.4 MB exact CSR
    unsigned* bufA      = (unsigned*)(ws + 15l * 1024 * 1024);      // bf16 H'  12.8 MB
    float*    bufB      = (float*)   (ws + 28l * 1024 * 1024);      // f32 hidden 25.6 MB

    const int edgeBlocks = (EE + 255) / 256;
    const int aggBlocks  = NN / 4;                   // 25000 exact
    const int gemmBlocks = (NN + 63) / 64;           // 1563
    const int tileBlocks = (EE + TILE - 1) / TILE;   // 98

    hipMemsetAsync(degI, 0, NN * sizeof(int), stream);
    hist_k<<<edgeBlocks, 256, 0, stream>>>(dstI, degI);
    dinv_k<<<NB, 256, 0, stream>>>(degI, dinv);
    scan1_k<<<NB, 256, 0, stream>>>(degI, cursor, bsum);
    scan2_k<<<1, 512, 0, stream>>>(bsum);
    scan3_k<<<NB, 256, 0, stream>>>(cursor, bsum);
    binit_k<<<2, 256, 0, stream>>>(cursor, bucketCur);
    bucket_k<<<tileBlocks, 256, 0, stream>>>(srcI, dstI, bucketCur, bE);
    reorder2_k<<<NBUCK, 256, 0, stream>>>(cursor, bE, csrSrc);
    fuse_k<<<1, 256, 0, stream>>>(mpW0, mpb0, mpW1, mpb1, Wf, bfv);

    // layer 0
    gemm_mfma<128><<<gemmBlocks, 256, 0, stream>>>(x, W0, dinv, bufA);
    agg_k<<<aggBlocks, 256, 0, stream>>>(cursor, degI, csrSrc, dinv, (const uint2*)bufA,
                                         (const float4*)b0, (const float4*)ln0g,
                                         (const float4*)ln0b, (float4*)bufB, 1);
    // layer 1
    gemm_mfma<64><<<gemmBlocks, 256, 0, stream>>>(bufB, W1, dinv, bufA);
    agg_k<<<aggBlocks, 256, 0, stream>>>(cursor, degI, csrSrc, dinv, (const uint2*)bufA,
                                         (const float4*)b1, (const float4*)ln1g,
                                         (const float4*)ln1b, (float4*)bufB, 1);
    // layer 2 (no LN) then fused MLP head via MFMA
    gemm_mfma<64><<<gemmBlocks, 256, 0, stream>>>(bufB, W2, dinv, bufA);
    agg_k<<<aggBlocks, 256, 0, stream>>>(cursor, degI, csrSrc, dinv, (const uint2*)bufA,
                                         (const float4*)b2, (const float4*)ln0g,
                                         (const float4*)ln0b, (float4*)bufB, 0);
    mlp_mfma<<<gemmBlocks, 256, 0, stream>>>(bufB, Wf, bfv, out);
}

// Round 12
// 454.762 us; speedup vs baseline: 5.5054x; 1.0858x over previous
//
#include <hip/hip_runtime.h>
#include <hip/hip_bf16.h>

#define NN 100000
#define EE 1600000
#define DOUT 40
#define LN_EPS 1e-5f
#define NB 391     // (NN+255)/256 scan blocks
#define NBUCK 391  // buckets of 256 dst nodes
#define TILE 4096
#define TBLK 391   // (EE+TILE-1)/TILE
#define BCAP 8192  // per-bucket capacity (expected 4092 +- 64)

typedef __attribute__((ext_vector_type(8))) short short8;   // 8 bf16 = 4 VGPRs
typedef __attribute__((ext_vector_type(4))) float f32x4;    // MFMA acc

// ---------------------------------------------------------------- bf16 helpers (RNE pack)
__device__ __forceinline__ float blo(unsigned u) { return __uint_as_float(u << 16); }
__device__ __forceinline__ float bhi(unsigned u) { return __uint_as_float(u & 0xffff0000u); }
__device__ __forceinline__ unsigned bpack(float lo, float hi) {
    unsigned a = __float_as_uint(lo);
    unsigned b = __float_as_uint(hi);
    a = (a + 0x7fffu + ((a >> 16) & 1u)) >> 16;
    b = (b + 0x7fffu + ((b >> 16) & 1u)) & 0xffff0000u;
    return (a & 0xffffu) | b;
}

// ---------------------------------------------------------------- bucket build (also produces degI)
__global__ void binit_k(int* __restrict__ bucketCur) {
    int b = blockIdx.x * 256 + threadIdx.x;
    if (b < NBUCK) bucketCur[b] = b * BCAP;
}

// 391 blocks x 4096 edges. Pass 1: per-wave LDS histogram + global degree.
// Claim: one global atomic per bucket per block (chunk-exclusive writes).
// Pass 2: scatter into fixed-capacity bucket regions, per-wave sub-chunks.
__global__ __launch_bounds__(256, 4) void bucket_k(const int* __restrict__ src,
                                                   const int* __restrict__ dst,
                                                   int* __restrict__ degI,
                                                   int* __restrict__ bucketCur,
                                                   unsigned* __restrict__ bE) {
    __shared__ int cnt[4][NBUCK];
    __shared__ int basew[4][NBUCK];
    int tid = threadIdx.x;
    int wv = tid >> 6;
    for (int i = tid; i < 4 * NBUCK; i += 256) ((int*)cnt)[i] = 0;
    __syncthreads();
    long e0 = (long)blockIdx.x * TILE;
    int d[16];
#pragma unroll
    for (int i = 0; i < 16; ++i) {
        long e = e0 + tid + i * 256;
        d[i] = (e < EE) ? dst[e] : -1;
    }
#pragma unroll
    for (int i = 0; i < 16; ++i) {
        if (d[i] >= 0) {
            atomicAdd(&degI[d[i]], 1);
            atomicAdd(&cnt[wv][d[i] >> 8], 1);
        }
    }
    __syncthreads();
    for (int b = tid; b < NBUCK; b += 256) {
        int c0 = cnt[0][b], c1 = cnt[1][b], c2 = cnt[2][b], c3 = cnt[3][b];
        int tot = c0 + c1 + c2 + c3;
        int base = tot ? atomicAdd(&bucketCur[b], tot) : 0;
        basew[0][b] = base;
        basew[1][b] = base + c0;
        basew[2][b] = base + c0 + c1;
        basew[3][b] = base + c0 + c1 + c2;
        cnt[0][b] = 0; cnt[1][b] = 0; cnt[2][b] = 0; cnt[3][b] = 0;
    }
    __syncthreads();
#pragma unroll
    for (int i = 0; i < 16; ++i) {
        if (d[i] >= 0) {
            long e = e0 + tid + i * 256;
            int b = d[i] >> 8;
            int pos = basew[wv][b] + atomicAdd(&cnt[wv][b], 1);
            bE[pos] = (unsigned)src[e] | ((unsigned)(d[i] & 255) << 24);
        }
    }
}

// ---------------------------------------------------------------- dinv + scan (cursor = START offsets)
__global__ void dinv_k(const int* __restrict__ degI, float* __restrict__ dinv) {
    int n = blockIdx.x * 256 + threadIdx.x;
    if (n < NN) dinv[n] = rsqrtf((float)degI[n] + 1.0f);
}

__global__ void scan1_k(const int* __restrict__ degI, int* __restrict__ cursor,
                        int* __restrict__ bsum) {
    __shared__ int s[256];
    int tid = threadIdx.x;
    int i = blockIdx.x * 256 + tid;
    int v = (i < NN) ? degI[i] : 0;
    s[tid] = v;
    __syncthreads();
    for (int off = 1; off < 256; off <<= 1) {
        int t = (tid >= off) ? s[tid - off] : 0;
        __syncthreads();
        s[tid] += t;
        __syncthreads();
    }
    if (i < NN) cursor[i] = s[tid] - v;
    if (tid == 255) bsum[blockIdx.x] = s[255];
}

__global__ void scan2_k(int* __restrict__ bsum) {
    __shared__ int s[512];
    int tid = threadIdx.x;
    int v = (tid < NB) ? bsum[tid] : 0;
    s[tid] = v;
    __syncthreads();
    for (int off = 1; off < 512; off <<= 1) {
        int t = (tid >= off) ? s[tid - off] : 0;
        __syncthreads();
        s[tid] += t;
        __syncthreads();
    }
    if (tid < NB) bsum[tid] = s[tid] - v;
}

__global__ void scan3_k(int* __restrict__ cursor, const int* __restrict__ bsum) {
    int i = blockIdx.x * 256 + threadIdx.x;
    if (i < NN) cursor[i] += bsum[blockIdx.x];
}

// ---------------------------------------------------------------- bucket -> exact CSR (writes stay in one 16KB window)
__global__ void reorder2_k(const int* __restrict__ cursor, const int* __restrict__ bucketCur,
                           const unsigned* __restrict__ bE, int* __restrict__ csrSrc) {
    __shared__ int sStart[256];
    int tid = threadIdx.x;
    int nodeBase = blockIdx.x << 8;
    int nd = nodeBase + tid;
    sStart[tid] = (nd < NN) ? cursor[nd] : EE;
    __syncthreads();
    int start = blockIdx.x * BCAP;
    int end = bucketCur[blockIdx.x];
    for (int e = start + tid; e < end; e += 256) {
        unsigned v = bE[e];
        int dl = v >> 24;
        int pos = atomicAdd(&sStart[dl], 1);
        csrSrc[pos] = (int)(v & 0xFFFFFFu);
    }
}

// ---------------------------------------------------------------- MFMA GEMM: H' = bf16((X@W)*dinv)
template <int K>
__global__ __launch_bounds__(256, 2) void gemm_mfma(const float* __restrict__ X,
                                                    const float* __restrict__ W,
                                                    const float* __restrict__ dinv,
                                                    unsigned* __restrict__ H) {
    constexpr int C = K / 32;
    __shared__ unsigned short sW16[K * 66];
    __shared__ float sD[64 * 65];
    int tid = threadIdx.x;
    for (int i = tid; i < K * 64; i += 256) {
        int k = i >> 6, n = i & 63;
        sW16[k * 66 + n] = (unsigned short)(bpack(W[i], 0.f) & 0xffffu);
    }
    __syncthreads();
    int wv = tid >> 6, lane = tid & 63;
    int q = lane >> 4, ln = lane & 15;
    short8 bfrag[C][4];
#pragma unroll
    for (int c = 0; c < C; ++c) {
#pragma unroll
        for (int t = 0; t < 4; ++t) {
            int kb = (c * 32 + q * 8) * 66 + t * 16 + ln;
            unsigned u0 = (unsigned)sW16[kb]       | ((unsigned)sW16[kb + 66]  << 16);
            unsigned u1 = (unsigned)sW16[kb + 132] | ((unsigned)sW16[kb + 198] << 16);
            unsigned u2 = (unsigned)sW16[kb + 264] | ((unsigned)sW16[kb + 330] << 16);
            unsigned u3 = (unsigned)sW16[kb + 396] | ((unsigned)sW16[kb + 462] << 16);
            uint4 u = make_uint4(u0, u1, u2, u3);
            bfrag[c][t] = __builtin_bit_cast(short8, u);
        }
    }
    int base = blockIdx.x * 64;
    int node = base + wv * 16 + ln;
    bool ok = node < NN;
    short8 afrag[C];
#pragma unroll
    for (int c = 0; c < C; ++c) {
        float4 f0 = make_float4(0.f, 0.f, 0.f, 0.f);
        float4 f1 = make_float4(0.f, 0.f, 0.f, 0.f);
        if (ok) {
            const float4* xp = (const float4*)(X + (long)node * K + c * 32 + q * 8);
            f0 = xp[0];
            f1 = xp[1];
        }
        uint4 u;
        u.x = bpack(f0.x, f0.y);
        u.y = bpack(f0.z, f0.w);
        u.z = bpack(f1.x, f1.y);
        u.w = bpack(f1.z, f1.w);
        afrag[c] = __builtin_bit_cast(short8, u);
    }
#pragma unroll
    for (int t = 0; t < 4; ++t) {
        f32x4 acc = {0.f, 0.f, 0.f, 0.f};
#pragma unroll
        for (int c = 0; c < C; ++c)
            acc = __builtin_amdgcn_mfma_f32_16x16x32_bf16(afrag[c], bfrag[c][t], acc, 0, 0, 0);
#pragma unroll
        for (int r = 0; r < 4; ++r)
            sD[(wv * 16 + q * 4 + r) * 65 + t * 16 + ln] = acc[r];
    }
    __syncthreads();
    for (int i = tid; i < 64 * 32; i += 256) {
        int row = i >> 5, c2 = i & 31;
        int nd = base + row;
        if (nd < NN) {
            float di = dinv[nd];
            float lo = sD[row * 65 + c2 * 2] * di;
            float hi = sD[row * 65 + c2 * 2 + 1] * di;
            H[nd * 32 + c2] = bpack(lo, hi);
        }
    }
}

// ---------------------------------------------------------------- aggregate + bias + relu + optional LN (proven clean)
__global__ __launch_bounds__(256, 4) void agg_k(
        const int* __restrict__ cursor, const int* __restrict__ degI,
        const int* __restrict__ csrSrc, const float* __restrict__ dinv,
        const uint2* __restrict__ H2, const float4* __restrict__ bias4,
        const float4* __restrict__ g4, const float4* __restrict__ beta4,
        float4* __restrict__ OUT4, int doLN) {
    int tid = threadIdx.x;
    int w = tid >> 6, lane = tid & 63;
    int g = lane >> 4;
    int f = lane & 15;
    int node = blockIdx.x * 4 + w;
    int start = cursor[node];
    int end = start + degI[node];
    float ax = 0.f, ay = 0.f, az = 0.f, aw = 0.f;
    float bx = 0.f, by = 0.f, bz = 0.f, bw = 0.f;
    int e = start + g;
    for (; e + 4 < end; e += 8) {
        int s0 = csrSrc[e];
        int s1 = csrSrc[e + 4];
        uint2 q0 = H2[(long)s0 * 16 + f];
        uint2 q1 = H2[(long)s1 * 16 + f];
        ax += blo(q0.x); ay += bhi(q0.x); az += blo(q0.y); aw += bhi(q0.y);
        bx += blo(q1.x); by += bhi(q1.x); bz += blo(q1.y); bw += bhi(q1.y);
    }
    if (e < end) {
        uint2 q0 = H2[(long)csrSrc[e] * 16 + f];
        ax += blo(q0.x); ay += bhi(q0.x); az += blo(q0.y); aw += bhi(q0.y);
    }
    ax += bx; ay += by; az += bz; aw += bw;
    ax += __shfl_xor(ax, 16); ay += __shfl_xor(ay, 16);
    az += __shfl_xor(az, 16); aw += __shfl_xor(aw, 16);
    ax += __shfl_xor(ax, 32); ay += __shfl_xor(ay, 32);
    az += __shfl_xor(az, 32); aw += __shfl_xor(aw, 32);
    float di = dinv[node];
    uint2 qs = H2[(long)node * 16 + f];
    float4 bb = bias4[f];
    float vx = fmaxf((ax + blo(qs.x)) * di + bb.x, 0.f);
    float vy = fmaxf((ay + bhi(qs.x)) * di + bb.y, 0.f);
    float vz = fmaxf((az + blo(qs.y)) * di + bb.z, 0.f);
    float vw = fmaxf((aw + bhi(qs.y)) * di + bb.w, 0.f);
    if (doLN) {
        float s = vx + vy + vz + vw;
        s += __shfl_xor(s, 1); s += __shfl_xor(s, 2);
        s += __shfl_xor(s, 4); s += __shfl_xor(s, 8);
        float mu = s * (1.f / 64.f);
        vx -= mu; vy -= mu; vz -= mu; vw -= mu;
        float vs = vx * vx + vy * vy + vz * vz + vw * vw;
        vs += __shfl_xor(vs, 1); vs += __shfl_xor(vs, 2);
        vs += __shfl_xor(vs, 4); vs += __shfl_xor(vs, 8);
        float inv = rsqrtf(vs * (1.f / 64.f) + LN_EPS);
        float4 gg = g4[f];
        float4 tt = beta4[f];
        vx = vx * inv * gg.x + tt.x;
        vy = vy * inv * gg.y + tt.y;
        vz = vz * inv * gg.z + tt.z;
        vw = vw * inv * gg.w + tt.w;
    }
    if (g == 0) OUT4[(long)node * 16 + f] = make_float4(vx, vy, vz, vw);
}

// ---------------------------------------------------------------- fuse the two head linears
__global__ void fuse_k(const float* __restrict__ W0, const float* __restrict__ b0,
                       const float* __restrict__ W1, const float* __restrict__ b1,
                       float* __restrict__ Wf, float* __restrict__ bf) {
    int tid = threadIdx.x;
    for (int i = tid; i < 64 * 48; i += 256) {
        int k = i / 48, n = i % 48;
        float acc = 0.f;
        if (n < DOUT) {
            for (int j = 0; j < 64; ++j) acc = fmaf(W0[k * 64 + j], W1[j * DOUT + n], acc);
        }
        Wf[i] = acc;
    }
    for (int n = tid; n < 48; n += 256) {
        float acc = 0.f;
        if (n < DOUT) {
            acc = b1[n];
            for (int j = 0; j < 64; ++j) acc = fmaf(b0[j], W1[j * DOUT + n], acc);
        }
        bf[n] = acc;
    }
}

// ---------------------------------------------------------------- MLP head via MFMA: OUT = Hin @ Wf + bf
__global__ __launch_bounds__(256, 2) void mlp_mfma(const float* __restrict__ Hin,
                                                   const float* __restrict__ Wf,
                                                   const float* __restrict__ bf,
                                                   float* __restrict__ OUT) {
    __shared__ unsigned short sW16[64 * 50];
    int tid = threadIdx.x;
    for (int i = tid; i < 64 * 48; i += 256) {
        int k = i / 48, n = i % 48;
        sW16[k * 50 + n] = (unsigned short)(bpack(Wf[i], 0.f) & 0xffffu);
    }
    __syncthreads();
    int wv = tid >> 6, lane = tid & 63;
    int q = lane >> 4, ln = lane & 15;
    short8 bfrag[2][3];
#pragma unroll
    for (int c = 0; c < 2; ++c) {
#pragma unroll
        for (int t = 0; t < 3; ++t) {
            int kb = (c * 32 + q * 8) * 50 + t * 16 + ln;
            unsigned u0 = (unsigned)sW16[kb]       | ((unsigned)sW16[kb + 50]  << 16);
            unsigned u1 = (unsigned)sW16[kb + 100] | ((unsigned)sW16[kb + 150] << 16);
            unsigned u2 = (unsigned)sW16[kb + 200] | ((unsigned)sW16[kb + 250] << 16);
            unsigned u3 = (unsigned)sW16[kb + 300] | ((unsigned)sW16[kb + 350] << 16);
            uint4 u = make_uint4(u0, u1, u2, u3);
            bfrag[c][t] = __builtin_bit_cast(short8, u);
        }
    }
    int base = blockIdx.x * 64;
    int node = base + wv * 16 + ln;
    bool ok = node < NN;
    short8 afrag[2];
#pragma unroll
    for (int c = 0; c < 2; ++c) {
        float4 f0 = make_float4(0.f, 0.f, 0.f, 0.f);
        float4 f1 = make_float4(0.f, 0.f, 0.f, 0.f);
        if (ok) {
            const float4* xp = (const float4*)(Hin + (long)node * 64 + c * 32 + q * 8);
            f0 = xp[0];
            f1 = xp[1];
        }
        uint4 u;
        u.x = bpack(f0.x, f0.y);
        u.y = bpack(f0.z, f0.w);
        u.z = bpack(f1.x, f1.y);
        u.w = bpack(f1.z, f1.w);
        afrag[c] = __builtin_bit_cast(short8, u);
    }
#pragma unroll
    for (int t = 0; t < 3; ++t) {
        f32x4 acc = {0.f, 0.f, 0.f, 0.f};
        acc = __builtin_amdgcn_mfma_f32_16x16x32_bf16(afrag[0], bfrag[0][t], acc, 0, 0, 0);
        acc = __builtin_amdgcn_mfma_f32_16x16x32_bf16(afrag[1], bfrag[1][t], acc, 0, 0, 0);
        int col = t * 16 + ln;
        if (col < DOUT) {
            float bv = bf[col];
#pragma unroll
            for (int r = 0; r < 4; ++r) {
                int nd = base + wv * 16 + q * 4 + r;
                if (nd < NN) OUT[(long)nd * DOUT + col] = acc[r] + bv;
            }
        }
    }
}

// ----------------------------------------------------------------
extern "C" void kernel_launch(void* const* d_in, const int* in_sizes, int n_in,
                              void* d_out, int out_size, void* d_ws, size_t ws_size,
                              hipStream_t stream) {
    const float* x    = (const float*)d_in[0];
    const int*   ei   = (const int*)d_in[1];
    const int*   srcI = ei;
    const int*   dstI = ei + EE;
    const float* W0   = (const float*)d_in[2];
    const float* b0   = (const float*)d_in[3];
    const float* W1   = (const float*)d_in[4];
    const float* b1   = (const float*)d_in[5];
    const float* W2   = (const float*)d_in[6];
    const float* b2   = (const float*)d_in[7];
    const float* ln0g = (const float*)d_in[8];
    const float* ln0b = (const float*)d_in[9];
    const float* ln1g = (const float*)d_in[10];
    const float* ln1b = (const float*)d_in[11];
    const float* mpW0 = (const float*)d_in[12];
    const float* mpb0 = (const float*)d_in[13];
    const float* mpW1 = (const float*)d_in[14];
    const float* mpb1 = (const float*)d_in[15];
    float* out = (float*)d_out;

    char* ws = (char*)d_ws;
    float*    dinv      = (float*)   (ws + 0);                      // 400 KB
    int*      degI      = (int*)     (ws + 512l * 1024);            // 400 KB
    int*      cursor    = (int*)     (ws + 1024l * 1024);           // 400 KB
    int*      bsum      = (int*)     (ws + 1536l * 1024);
    int*      bucketCur = (int*)     (ws + 1600l * 1024);
    float*    Wf        = (float*)   (ws + 1792l * 1024);
    float*    bfv       = (float*)   (ws + 1984l * 1024);
    unsigned* bE        = (unsigned*)(ws + 2048l * 1024);           // 391*8192*4 = 12.8 MB
    int*      csrSrc    = (int*)     (ws + 15l * 1024 * 1024);      // 6.4 MB
    unsigned* bufA      = (unsigned*)(ws + 22l * 1024 * 1024);      // bf16 H' 12.8 MB
    float*    bufB      = (float*)   (ws + 35l * 1024 * 1024);      // f32 hidden 25.6 MB

    const int aggBlocks  = NN / 4;             // 25000 exact
    const int gemmBlocks = (NN + 63) / 64;     // 1563

    hipMemsetAsync(degI, 0, NN * sizeof(int), stream);
    binit_k<<<2, 256, 0, stream>>>(bucketCur);
    bucket_k<<<TBLK, 256, 0, stream>>>(srcI, dstI, degI, bucketCur, bE);
    dinv_k<<<NB, 256, 0, stream>>>(degI, dinv);
    scan1_k<<<NB, 256, 0, stream>>>(degI, cursor, bsum);
    scan2_k<<<1, 512, 0, stream>>>(bsum);
    scan3_k<<<NB, 256, 0, stream>>>(cursor, bsum);
    reorder2_k<<<NBUCK, 256, 0, stream>>>(cursor, bucketCur, bE, csrSrc);
    fuse_k<<<1, 256, 0, stream>>>(mpW0, mpb0, mpW1, mpb1, Wf, bfv);

    // layer 0
    gemm_mfma<128><<<gemmBlocks, 256, 0, stream>>>(x, W0, dinv, bufA);
    agg_k<<<aggBlocks, 256, 0, stream>>>(cursor, degI, csrSrc, dinv, (const uint2*)bufA,
                                         (const float4*)b0, (const float4*)ln0g,
                                         (const float4*)ln0b, (float4*)bufB, 1);
    // layer 1
    gemm_mfma<64><<<gemmBlocks, 256, 0, stream>>>(bufB, W1, dinv, bufA);
    agg_k<<<aggBlocks, 256, 0, stream>>>(cursor, degI, csrSrc, dinv, (const uint2*)bufA,
                                         (const float4*)b1, (const float4*)ln1g,
                                         (const float4*)ln1b, (float4*)bufB, 1);
    // layer 2 (no LN) then fused MLP head via MFMA
    gemm_mfma<64><<<gemmBlocks, 256, 0, stream>>>(bufB, W2, dinv, bufA);
    agg_k<<<aggBlocks, 256, 0, stream>>>(cursor, degI, csrSrc, dinv, (const uint2*)bufA,
                                         (const float4*)b2, (const float4*)ln0g,
                                         (const float4*)ln0b, (float4*)bufB, 0);
    mlp_mfma<<<gemmBlocks, 256, 0, stream>>>(bufB, Wf, bfv, out);
}